// Round 5
// baseline (6427.325 us; speedup 1.0000x reference)
//
#include <hip/hip_runtime.h>
#include <hip/hip_bf16.h>

// MimiEuclideanCodebook — MFMA candidate scan + np-bit-exact rescore.
// scan1 (bf16 MFMA): rowmin of approx d2a. scan2 (identical MFMA): candidates
// with d2a <= rowmin + DELTA (capture margin >> error bound). rescore: np-exact
// OpenBLAS-style fp32 FMA chain on candidates only, lex-min (value, idx).
// Fallback (count > SLOTS): full-row exact scan. All outputs decided by the
// round-4-verified exact path.

typedef float f32x4 __attribute__((ext_vector_type(4)));
typedef short s16x4 __attribute__((ext_vector_type(4)));
typedef short s16x8 __attribute__((ext_vector_type(8)));

#define D_DIM 256
#define N_ROWS 65536
#define K_CODES 2048
#define VQ_EPS 1e-5f
#define DELTA 4.0f
#define SLOTS 16

__device__ __forceinline__ short bf16s(float f) {
    __hip_bfloat16 h = __float2bfloat16(f);
    return __builtin_bit_cast(short, h);
}
__device__ __forceinline__ unsigned fkey(float f) {      // order-preserving u32
    unsigned u = __float_as_uint(f);
    return (u & 0x80000000u) ? ~u : (u | 0x80000000u);
}
__device__ __forceinline__ float funkey(unsigned k) {
    unsigned u = (k & 0x80000000u) ? (k ^ 0x80000000u) : ~k;
    return __uint_as_float(u);
}

// ---------------- prep: embed = embed_sum / clip(usage) -----------------------
__global__ void prep_embed(const float* __restrict__ es, const float* __restrict__ us,
                           float* __restrict__ embed) {
    int i = blockIdx.x * 256 + threadIdx.x;               // 524288
    int k = i >> 8;
    float u = fmaxf(us[k], VQ_EPS);
    embed[i] = es[i] / u;                                 // IEEE div == np bitwise
}

// numpy pairwise sum of squares over 256 (verified round 4)
__device__ __forceinline__ void np_sumsq_16lane(const float* a, float* out, int g) {
#pragma clang fp contract(off)
    int j = g & 7, h = g >> 3;
    const float* p = a + h * 128;
    float t = p[j];
    float r = t * t;
#pragma unroll
    for (int i = 1; i < 16; ++i) { float v = p[j + 8 * i]; r += v * v; }
    r += __shfl_xor(r, 1);
    r += __shfl_xor(r, 2);
    r += __shfl_xor(r, 4);
    float other = __shfl_xor(r, 8);
    if (g == 0) *out = r + other;
}

__global__ void prep_e2(const float* __restrict__ embed, float* __restrict__ e2) {
    int gid = blockIdx.x * 256 + threadIdx.x;             // 2048 * 16
    int k = gid >> 4;
    np_sumsq_16lane(embed + k * D_DIM, e2 + k, threadIdx.x & 15);
}

__global__ void prep_x2(const float* __restrict__ x, float* __restrict__ x2,
                        unsigned* __restrict__ rowmin, unsigned* __restrict__ counts) {
    int gid = blockIdx.x * 256 + threadIdx.x;             // 65536 * 16
    int r = gid >> 4;
    int g = threadIdx.x & 15;
    np_sumsq_16lane(x + r * D_DIM, x2 + r, g);
    if (g == 1) rowmin[r] = 0xFFFFFFFFu;                  // above every fkey
    if (g == 2) counts[r] = 0u;
}

// ---------------- bf16 MFMA scan: BUILD=0 rowmin, BUILD=1 candidates ----------
template <int BUILD>
__launch_bounds__(256, 2)
__global__ void vq_scan(const float* __restrict__ x, const float* __restrict__ embed,
                        const float* __restrict__ e2, const float* __restrict__ x2,
                        unsigned* __restrict__ rowmin, unsigned* __restrict__ counts,
                        unsigned short* __restrict__ cands) {
    __shared__ short lA[128][40];                         // bf16 bits, stride 40 (2-way only)
    __shared__ short lB[128][40];

    const int mt = blockIdx.x >> 4, nt = blockIdx.x & 15;
    const int m_base = mt * 128, n_base = nt * 128;
    const int tid = threadIdx.x, lane = tid & 63, wid = tid >> 6;
    const int wm = wid >> 1, wn = wid & 1;                // 2x2 waves, 64x64 each
    const int rb = wm * 64, cb = wn * 64;
    const int l15 = lane & 15, lg = lane >> 4;
    const int srow = tid >> 1, sseg = tid & 1;            // staging: row, 16-float half

    f32x4 acc[4][4];
#pragma unroll
    for (int m = 0; m < 4; ++m)
#pragma unroll
        for (int n = 0; n < 4; ++n) { f32x4 z = {0.f, 0.f, 0.f, 0.f}; acc[m][n] = z; }

    f32x4 rA[4], rB[4];
    auto gload = [&](int kc) {
#pragma unroll
        for (int v = 0; v < 4; ++v)
            rA[v] = *(const f32x4*)&x[(m_base + srow) * D_DIM + kc * 32 + sseg * 16 + v * 4];
#pragma unroll
        for (int v = 0; v < 4; ++v)
            rB[v] = *(const f32x4*)&embed[(n_base + srow) * D_DIM + kc * 32 + sseg * 16 + v * 4];
    };
    auto swrite = [&]() {
#pragma unroll
        for (int v = 0; v < 4; ++v) {
            s16x4 a, b;
#pragma unroll
            for (int j = 0; j < 4; ++j) { a[j] = bf16s(rA[v][j]); b[j] = bf16s(rB[v][j]); }
            *(s16x4*)&lA[srow][sseg * 16 + v * 4] = a;    // 8B aligned (stride 80B)
            *(s16x4*)&lB[srow][sseg * 16 + v * 4] = b;
        }
    };
    auto compute = [&]() {
        s16x8 af[4], bf[4];
#pragma unroll
        for (int m = 0; m < 4; ++m)
            af[m] = *(const s16x8*)&lA[rb + m * 16 + l15][lg * 8];
#pragma unroll
        for (int n = 0; n < 4; ++n)
            bf[n] = *(const s16x8*)&lB[cb + n * 16 + l15][lg * 8];
#pragma unroll
        for (int m = 0; m < 4; ++m)
#pragma unroll
            for (int n = 0; n < 4; ++n)
                acc[m][n] = __builtin_amdgcn_mfma_f32_16x16x32_bf16(af[m], bf[n], acc[m][n], 0, 0, 0);
    };

    gload(0);
#pragma unroll 1
    for (int kc = 0; kc < 8; ++kc) {
        __syncthreads();
        swrite();
        __syncthreads();
        if (kc < 7) gload(kc + 1);
        compute();
    }

    // epilogue: d2a = (x2 - 2*xe_a) + e2  (identical dataflow in both builds)
    // C/D layout (m89-verified): col = lane&15, row = (lane>>4)*4 + reg
    const int grow0 = m_base + rb + lg * 4;               // + m*16 + j
    const int gcol0 = n_base + cb + l15;                  // + n*16
    float e2v[4];
#pragma unroll
    for (int n = 0; n < 4; ++n) e2v[n] = e2[gcol0 + n * 16];

#pragma unroll
    for (int m = 0; m < 4; ++m) {
#pragma unroll
        for (int j = 0; j < 4; ++j) {
            int gr = grow0 + m * 16 + j;
            float x2v = x2[gr];
            if (BUILD == 0) {
                float mn = __builtin_inff();
#pragma unroll
                for (int n = 0; n < 4; ++n) {
                    float d2 = (x2v - 2.0f * acc[m][n][j]) + e2v[n];
                    mn = fminf(mn, d2);
                }
#pragma unroll
                for (int s = 1; s < 16; s <<= 1) mn = fminf(mn, __shfl_xor(mn, s));
                if (l15 == 0) atomicMin(&rowmin[gr], fkey(mn));
            } else {
                float thr = funkey(rowmin[gr]) + DELTA;
#pragma unroll
                for (int n = 0; n < 4; ++n) {
                    float d2 = (x2v - 2.0f * acc[m][n][j]) + e2v[n];
                    if (d2 <= thr) {
                        unsigned p = atomicAdd(&counts[gr], 1u);
                        if (p < SLOTS) cands[gr * SLOTS + p] = (unsigned short)(gcol0 + n * 16);
                    }
                }
            }
        }
    }
}

// ---------------- np-exact rescore of candidates (1 wave per row) -------------
__launch_bounds__(256, 4)
__global__ void vq_rescore(const float* __restrict__ x, const float* __restrict__ embed,
                           const float* __restrict__ e2, const float* __restrict__ x2,
                           const unsigned* __restrict__ counts,
                           const unsigned short* __restrict__ cands,
                           float* __restrict__ out) {
    const int r = blockIdx.x * 4 + (threadIdx.x >> 6);
    const int lane = threadIdx.x & 63;
    const unsigned cnt = counts[r];
    float bv; int bi;

    if (cnt <= SLOTS) {
        int code = (lane < (int)cnt) ? (int)cands[r * SLOTS + lane] : 0;
        float t = 0.0f;
#pragma unroll 8
        for (int k4 = 0; k4 < 64; ++k4) {                 // single chain, k ascending
            f32x4 a4 = *(const f32x4*)&x[r * D_DIM + k4 * 4];     // wave-uniform bcast
            f32x4 e4 = *(const f32x4*)&embed[code * D_DIM + k4 * 4];
            t = __builtin_fmaf(a4[0], e4[0], t);
            t = __builtin_fmaf(a4[1], e4[1], t);
            t = __builtin_fmaf(a4[2], e4[2], t);
            t = __builtin_fmaf(a4[3], e4[3], t);
        }
        bv = (x2[r] - 2.0f * t) + e2[code];
        bi = code;
        if (lane >= (int)cnt) { bv = __builtin_inff(); bi = 0x7FFFFFFF; }
    } else {
        // overflow fallback: exact scan of ALL codes (lane handles code q*64+lane)
        bv = __builtin_inff(); bi = 0x7FFFFFFF;
#pragma unroll 1
        for (int q = 0; q < 32; ++q) {
            int code = q * 64 + lane;
            float t = 0.0f;
#pragma unroll 8
            for (int k4 = 0; k4 < 64; ++k4) {
                f32x4 a4 = *(const f32x4*)&x[r * D_DIM + k4 * 4];
                f32x4 e4 = *(const f32x4*)&embed[code * D_DIM + k4 * 4];
                t = __builtin_fmaf(a4[0], e4[0], t);
                t = __builtin_fmaf(a4[1], e4[1], t);
                t = __builtin_fmaf(a4[2], e4[2], t);
                t = __builtin_fmaf(a4[3], e4[3], t);
            }
            float d2 = (x2[r] - 2.0f * t) + e2[code];
            if (d2 < bv) { bv = d2; bi = code; }          // ascending -> first-min
        }
    }
#pragma unroll
    for (int s = 1; s < 64; s <<= 1) {                    // lex (value, idx) min
        float ov = __shfl_xor(bv, s);
        int oi = __shfl_xor(bi, s);
        if (ov < bv || (ov == bv && oi < bi)) { bv = ov; bi = oi; }
    }
    if (lane == 0) out[r] = (float)bi;
}

// ---------------- gather quantized = es[idx]/max(us,eps) ----------------------
__global__ void vq_gather(const float* __restrict__ out_idx, const float* __restrict__ es,
                          const float* __restrict__ us, float* __restrict__ outq) {
    const int r = blockIdx.x * 4 + (threadIdx.x >> 6);
    const int lane = threadIdx.x & 63;
    const int bi = (int)out_idx[r];                       // exact for idx < 2048
    float u = fmaxf(us[bi], VQ_EPS);
    f32x4 v = *(const f32x4*)&es[bi * D_DIM + lane * 4];
    f32x4 o;
#pragma unroll
    for (int j = 0; j < 4; ++j) o[j] = v[j] / u;          // IEEE div == np bitwise
    *(f32x4*)&outq[r * D_DIM + lane * 4] = o;
}

extern "C" void kernel_launch(void* const* d_in, const int* in_sizes, int n_in,
                              void* d_out, int out_size, void* d_ws, size_t ws_size,
                              hipStream_t stream) {
    const float* x = (const float*)d_in[0];               // [65536, 256]
    const float* es = (const float*)d_in[1];              // [2048, 256]
    const float* us = (const float*)d_in[2];              // [2048]
    float* out = (float*)d_out;

    char* w = (char*)d_ws;                                // total 4,988,928 B
    float* e2             = (float*)(w);                  //      8,192
    float* x2             = (float*)(w + 8192);           //    262,144
    unsigned* rowmin      = (unsigned*)(w + 270336);      //    262,144
    unsigned* counts      = (unsigned*)(w + 532480);      //    262,144
    unsigned short* cands = (unsigned short*)(w + 794624);//  2,097,152
    float* embed          = (float*)(w + 2891776);        //  2,097,152

    hipLaunchKernelGGL(prep_embed, dim3(2048), dim3(256), 0, stream, es, us, embed);
    hipLaunchKernelGGL(prep_e2, dim3(128), dim3(256), 0, stream, embed, e2);
    hipLaunchKernelGGL(prep_x2, dim3(4096), dim3(256), 0, stream, x, x2, rowmin, counts);
    hipLaunchKernelGGL((vq_scan<0>), dim3(8192), dim3(256), 0, stream,
                       x, embed, e2, x2, rowmin, counts, cands);
    hipLaunchKernelGGL((vq_scan<1>), dim3(8192), dim3(256), 0, stream,
                       x, embed, e2, x2, rowmin, counts, cands);
    hipLaunchKernelGGL(vq_rescore, dim3(16384), dim3(256), 0, stream,
                       x, embed, e2, x2, counts, cands, out);
    hipLaunchKernelGGL(vq_gather, dim3(16384), dim3(256), 0, stream,
                       out, es, us, out + N_ROWS);
}

// Round 6
// 692.725 us; speedup vs baseline: 9.2783x; 9.2783x over previous
//
#include <hip/hip_runtime.h>
#include <hip/hip_bf16.h>

// MimiEuclideanCodebook — MFMA candidate scan + np-bit-exact rescore.
// scan1 (bf16 MFMA): rowmin of approx d2a. scan2 (identical MFMA): candidates
// with d2a <= rowmin + DELTA. rescore: np-exact OpenBLAS-style fp32 FMA chain
// on candidates only, lex-min (value, idx). Fallback (count > SLOTS): full-row
// exact scan (rare; DELTA=1.0 is >=25-sigma vs bf16 error for near-min codes).

typedef float f32x4 __attribute__((ext_vector_type(4)));
typedef short s16x4 __attribute__((ext_vector_type(4)));
typedef short s16x8 __attribute__((ext_vector_type(8)));

#define D_DIM 256
#define N_ROWS 65536
#define K_CODES 2048
#define VQ_EPS 1e-5f
#define DELTA 1.0f
#define SLOTS 32

__device__ __forceinline__ short bf16s(float f) {
    __hip_bfloat16 h = __float2bfloat16(f);
    return __builtin_bit_cast(short, h);
}
__device__ __forceinline__ unsigned fkey(float f) {      // order-preserving u32
    unsigned u = __float_as_uint(f);
    return (u & 0x80000000u) ? ~u : (u | 0x80000000u);
}
__device__ __forceinline__ float funkey(unsigned k) {
    unsigned u = (k & 0x80000000u) ? (k ^ 0x80000000u) : ~k;
    return __uint_as_float(u);
}

// ---------------- prep: embed = embed_sum / clip(usage) -----------------------
__global__ void prep_embed(const float* __restrict__ es, const float* __restrict__ us,
                           float* __restrict__ embed) {
    int i = blockIdx.x * 256 + threadIdx.x;               // 524288
    int k = i >> 8;
    float u = fmaxf(us[k], VQ_EPS);
    embed[i] = es[i] / u;                                 // IEEE div == np bitwise
}

// numpy pairwise sum of squares over 256 (verified round 4)
__device__ __forceinline__ void np_sumsq_16lane(const float* a, float* out, int g) {
#pragma clang fp contract(off)
    int j = g & 7, h = g >> 3;
    const float* p = a + h * 128;
    float t = p[j];
    float r = t * t;
#pragma unroll
    for (int i = 1; i < 16; ++i) { float v = p[j + 8 * i]; r += v * v; }
    r += __shfl_xor(r, 1);
    r += __shfl_xor(r, 2);
    r += __shfl_xor(r, 4);
    float other = __shfl_xor(r, 8);
    if (g == 0) *out = r + other;
}

__global__ void prep_e2(const float* __restrict__ embed, float* __restrict__ e2) {
    int gid = blockIdx.x * 256 + threadIdx.x;             // 2048 * 16
    int k = gid >> 4;
    np_sumsq_16lane(embed + k * D_DIM, e2 + k, threadIdx.x & 15);
}

__global__ void prep_x2(const float* __restrict__ x, float* __restrict__ x2,
                        unsigned* __restrict__ rowmin, unsigned* __restrict__ counts) {
    int gid = blockIdx.x * 256 + threadIdx.x;             // 65536 * 16
    int r = gid >> 4;
    int g = threadIdx.x & 15;
    np_sumsq_16lane(x + r * D_DIM, x2 + r, g);
    if (g == 1) rowmin[r] = 0xFFFFFFFFu;                  // above every fkey
    if (g == 2) counts[r] = 0u;
}

// ---------------- bf16 MFMA scan: BUILD=0 rowmin, BUILD=1 candidates ----------
template <int BUILD>
__launch_bounds__(256, 2)
__global__ void vq_scan(const float* __restrict__ x, const float* __restrict__ embed,
                        const float* __restrict__ e2, const float* __restrict__ x2,
                        unsigned* __restrict__ rowmin, unsigned* __restrict__ counts,
                        unsigned short* __restrict__ cands) {
    __shared__ short lA[128][40];                         // bf16 bits, stride 40
    __shared__ short lB[128][40];

    const int mt = blockIdx.x >> 4, nt = blockIdx.x & 15;
    const int m_base = mt * 128, n_base = nt * 128;
    const int tid = threadIdx.x, lane = tid & 63, wid = tid >> 6;
    const int wm = wid >> 1, wn = wid & 1;                // 2x2 waves, 64x64 each
    const int rb = wm * 64, cb = wn * 64;
    const int l15 = lane & 15, lg = lane >> 4;
    const int srow = tid >> 1, sseg = tid & 1;            // staging: row, 16-float half

    f32x4 acc[4][4];
#pragma unroll
    for (int m = 0; m < 4; ++m)
#pragma unroll
        for (int n = 0; n < 4; ++n) { f32x4 z = {0.f, 0.f, 0.f, 0.f}; acc[m][n] = z; }

    f32x4 rA[4], rB[4];
    auto gload = [&](int kc) {
#pragma unroll
        for (int v = 0; v < 4; ++v)
            rA[v] = *(const f32x4*)&x[(m_base + srow) * D_DIM + kc * 32 + sseg * 16 + v * 4];
#pragma unroll
        for (int v = 0; v < 4; ++v)
            rB[v] = *(const f32x4*)&embed[(n_base + srow) * D_DIM + kc * 32 + sseg * 16 + v * 4];
    };
    auto swrite = [&]() {
#pragma unroll
        for (int v = 0; v < 4; ++v) {
            s16x4 a, b;
#pragma unroll
            for (int j = 0; j < 4; ++j) { a[j] = bf16s(rA[v][j]); b[j] = bf16s(rB[v][j]); }
            *(s16x4*)&lA[srow][sseg * 16 + v * 4] = a;
            *(s16x4*)&lB[srow][sseg * 16 + v * 4] = b;
        }
    };
    auto compute = [&]() {
        s16x8 af[4], bf[4];
#pragma unroll
        for (int m = 0; m < 4; ++m)
            af[m] = *(const s16x8*)&lA[rb + m * 16 + l15][lg * 8];
#pragma unroll
        for (int n = 0; n < 4; ++n)
            bf[n] = *(const s16x8*)&lB[cb + n * 16 + l15][lg * 8];
#pragma unroll
        for (int m = 0; m < 4; ++m)
#pragma unroll
            for (int n = 0; n < 4; ++n)
                acc[m][n] = __builtin_amdgcn_mfma_f32_16x16x32_bf16(af[m], bf[n], acc[m][n], 0, 0, 0);
    };

    gload(0);
#pragma unroll 1
    for (int kc = 0; kc < 8; ++kc) {
        __syncthreads();                                  // prev compute done
        swrite();
        __syncthreads();                                  // LDS visible
        if (kc < 7) gload(kc + 1);
        compute();
    }

    // epilogue: d2a = (x2 - 2*xe_a) + e2
    // C/D layout (m89-verified): col = lane&15, row = (lane>>4)*4 + reg
    const int grow0 = m_base + rb + lg * 4;               // + m*16 + j
    const int gcol0 = n_base + cb + l15;                  // + n*16
    float e2v[4];
#pragma unroll
    for (int n = 0; n < 4; ++n) e2v[n] = e2[gcol0 + n * 16];

#pragma unroll
    for (int m = 0; m < 4; ++m) {
#pragma unroll
        for (int j = 0; j < 4; ++j) {
            int gr = grow0 + m * 16 + j;
            float x2v = x2[gr];
            if (BUILD == 0) {
                float mn = __builtin_inff();
#pragma unroll
                for (int n = 0; n < 4; ++n) {
                    float d2 = (x2v - 2.0f * acc[m][n][j]) + e2v[n];
                    mn = fminf(mn, d2);
                }
#pragma unroll
                for (int s = 1; s < 16; s <<= 1) mn = fminf(mn, __shfl_xor(mn, s));
                if (l15 == 0) atomicMin(&rowmin[gr], fkey(mn));
            } else {
                float thr = funkey(rowmin[gr]) + DELTA;
#pragma unroll
                for (int n = 0; n < 4; ++n) {
                    float d2 = (x2v - 2.0f * acc[m][n][j]) + e2v[n];
                    if (d2 <= thr) {
                        unsigned p = atomicAdd(&counts[gr], 1u);
                        if (p < SLOTS) cands[gr * SLOTS + p] = (unsigned short)(gcol0 + n * 16);
                    }
                }
            }
        }
    }
}

// ---------------- np-exact rescore of candidates (1 wave per row) -------------
__launch_bounds__(256, 4)
__global__ void vq_rescore(const float* __restrict__ x, const float* __restrict__ embed,
                           const float* __restrict__ e2, const float* __restrict__ x2,
                           const unsigned* __restrict__ counts,
                           const unsigned short* __restrict__ cands,
                           float* __restrict__ out) {
    const int r = blockIdx.x * 4 + (threadIdx.x >> 6);
    const int lane = threadIdx.x & 63;
    const unsigned cnt = counts[r];
    float bv; int bi;

    if (cnt <= SLOTS) {
        int code = (lane < (int)cnt) ? (int)cands[r * SLOTS + lane] : 0;
        float t = 0.0f;
#pragma unroll 8
        for (int k4 = 0; k4 < 64; ++k4) {                 // single chain, k ascending
            f32x4 a4 = *(const f32x4*)&x[r * D_DIM + k4 * 4];     // wave-uniform bcast
            f32x4 e4 = *(const f32x4*)&embed[code * D_DIM + k4 * 4];
            t = __builtin_fmaf(a4[0], e4[0], t);
            t = __builtin_fmaf(a4[1], e4[1], t);
            t = __builtin_fmaf(a4[2], e4[2], t);
            t = __builtin_fmaf(a4[3], e4[3], t);
        }
        bv = (x2[r] - 2.0f * t) + e2[code];
        bi = code;
        if (lane >= (int)cnt) { bv = __builtin_inff(); bi = 0x7FFFFFFF; }
    } else {
        // overflow fallback: exact scan of ALL codes (lane handles code q*64+lane)
        bv = __builtin_inff(); bi = 0x7FFFFFFF;
#pragma unroll 1
        for (int q = 0; q < 32; ++q) {
            int code = q * 64 + lane;
            float t = 0.0f;
#pragma unroll 8
            for (int k4 = 0; k4 < 64; ++k4) {
                f32x4 a4 = *(const f32x4*)&x[r * D_DIM + k4 * 4];
                f32x4 e4 = *(const f32x4*)&embed[code * D_DIM + k4 * 4];
                t = __builtin_fmaf(a4[0], e4[0], t);
                t = __builtin_fmaf(a4[1], e4[1], t);
                t = __builtin_fmaf(a4[2], e4[2], t);
                t = __builtin_fmaf(a4[3], e4[3], t);
            }
            float d2 = (x2[r] - 2.0f * t) + e2[code];
            if (d2 < bv) { bv = d2; bi = code; }          // ascending -> first-min
        }
    }
#pragma unroll
    for (int s = 1; s < 64; s <<= 1) {                    // lex (value, idx) min
        float ov = __shfl_xor(bv, s);
        int oi = __shfl_xor(bi, s);
        if (ov < bv || (ov == bv && oi < bi)) { bv = ov; bi = oi; }
    }
    if (lane == 0) out[r] = (float)bi;
}

// ---------------- gather quantized = es[idx]/max(us,eps) ----------------------
__global__ void vq_gather(const float* __restrict__ out_idx, const float* __restrict__ es,
                          const float* __restrict__ us, float* __restrict__ outq) {
    const int r = blockIdx.x * 4 + (threadIdx.x >> 6);
    const int lane = threadIdx.x & 63;
    const int bi = (int)out_idx[r];                       // exact for idx < 2048
    float u = fmaxf(us[bi], VQ_EPS);
    f32x4 v = *(const f32x4*)&es[bi * D_DIM + lane * 4];
    f32x4 o;
#pragma unroll
    for (int j = 0; j < 4; ++j) o[j] = v[j] / u;          // IEEE div == np bitwise
    *(f32x4*)&outq[r * D_DIM + lane * 4] = o;
}

extern "C" void kernel_launch(void* const* d_in, const int* in_sizes, int n_in,
                              void* d_out, int out_size, void* d_ws, size_t ws_size,
                              hipStream_t stream) {
    const float* x = (const float*)d_in[0];               // [65536, 256]
    const float* es = (const float*)d_in[1];              // [2048, 256]
    const float* us = (const float*)d_in[2];              // [2048]
    float* out = (float*)d_out;

    char* w = (char*)d_ws;                                // total 7,086,080 B
    float* e2             = (float*)(w);                  //      8,192
    float* x2             = (float*)(w + 8192);           //    262,144
    unsigned* rowmin      = (unsigned*)(w + 270336);      //    262,144
    unsigned* counts      = (unsigned*)(w + 532480);      //    262,144
    unsigned short* cands = (unsigned short*)(w + 794624);//  4,194,304 (SLOTS=32)
    float* embed          = (float*)(w + 4988928);        //  2,097,152

    hipLaunchKernelGGL(prep_embed, dim3(2048), dim3(256), 0, stream, es, us, embed);
    hipLaunchKernelGGL(prep_e2, dim3(128), dim3(256), 0, stream, embed, e2);
    hipLaunchKernelGGL(prep_x2, dim3(4096), dim3(256), 0, stream, x, x2, rowmin, counts);
    hipLaunchKernelGGL((vq_scan<0>), dim3(8192), dim3(256), 0, stream,
                       x, embed, e2, x2, rowmin, counts, cands);
    hipLaunchKernelGGL((vq_scan<1>), dim3(8192), dim3(256), 0, stream,
                       x, embed, e2, x2, rowmin, counts, cands);
    hipLaunchKernelGGL(vq_rescore, dim3(16384), dim3(256), 0, stream,
                       x, embed, e2, x2, counts, cands, out);
    hipLaunchKernelGGL(vq_gather, dim3(16384), dim3(256), 0, stream,
                       out, es, us, out + N_ROWS);
}